// Round 6
// baseline (474.460 us; speedup 1.0000x reference)
//
#include <hip/hip_runtime.h>

// self_attention: B=4, C=512, C8=64, N=64*64=4096
// R12: k_attn i-split across 2 blocks/CU. R11 post-mortem: FF depth-2 null ->
// R9's stall is NOT single-wave exposed load latency; it's 2-waves/SIMD can't
// cover exp-chain/LDS/barrier-skew stalls (MFMA pipe 43% busy, floor ~45us).
// R7 lesson: more waves only if total VMEM unchanged. i-axis split does that:
// grid 512 = (b, jt64, ipar); block processes its 32 i-chunks (disjoint hvf/ff
// halves, S splits too - no duplication unlike R8). 2x512thr blocks/CU = 4
// waves/SIMD. launch_bounds(512,4) caps VGPR 128 (have 96). Epilogue: k_zero
// pre-zeroes out; both blocks atomicAdd gamma*acc (+x for ipar0) - exactly 2
// commutative f32 adds/address -> bitwise-deterministic across replays.
// Locality: combo=L&7=(b,ipar)->XCD: hvf-half 2MB + ff 0.5MB < 4MB L2.
// Loop body is EXACTLY R9's (verified): pre-barrier FF(next)+HV issue,
// lgkm-only drain barrier, computeS(next), doPV. pt dbuf by local k&1.

#define Bq 4
#define Cq 512
#define Nq 4096
#define PSTR 72   // P^T row stride in shorts (144 B = 9*16 -> b128-aligned rows)

typedef __attribute__((ext_vector_type(8))) short bf16x8;
typedef __attribute__((ext_vector_type(4))) float f32x4;

__device__ __forceinline__ short f2bf(float f) {
  unsigned u = __float_as_uint(f);
  u += 0x7fffu + ((u >> 16) & 1u);   // RNE
  return (short)(u >> 16);
}
__device__ __forceinline__ float bf2f(short h) {
  return __uint_as_float(((unsigned)(unsigned short)h) << 16);
}

#define MFMA16(A, B, C) __builtin_amdgcn_mfma_f32_16x16x32_bf16((A), (B), (C), 0, 0, 0)

// frag base (in shorts) for f/g token-tile t16 (16 tokens), k-chunk ss (32 of 64)
__device__ __forceinline__ size_t fg_frag(int b, int t16, int ss) {
  return ((size_t)((b * 256 + t16) * 2 + ss)) * 512;
}
// frag base for hv c-tile tc (16 c), i-chunk si (32 of 4096)
__device__ __forceinline__ size_t hv_frag(int b, int tc, int si) {
  return ((size_t)((b * 32 + tc) * 128 + si)) * 512;
}

// ---------------- K_prepw: W splits ----------------
__global__ __launch_bounds__(256) void k_prepw(
    const float* __restrict__ Wf, const float* __restrict__ Wg,
    const float* __restrict__ Wh,
    short* __restrict__ whi, short* __restrict__ wlo, short* __restrict__ whb) {
  int gid = blockIdx.x * 256 + threadIdx.x;  // 0..262143
  if (gid < 128 * 512) {
    int row = gid >> 9;
    float v = (row < 64) ? Wf[gid] : Wg[gid - 32768];
    short h = f2bf(v);
    whi[gid] = h;
    wlo[gid] = f2bf(v - bf2f(h));
  }
  whb[gid] = f2bf(Wh[gid]);
}

// ---------------- K_xpose: x (B,C,N) fp32 -> XT (B,N,C) bf16 hi/lo ----------------
__global__ __launch_bounds__(256) void k_xpose(
    const float* __restrict__ x, short* __restrict__ xthi, short* __restrict__ xtlo) {
  int b = blockIdx.z, c0 = blockIdx.y * 64, n0 = blockIdx.x * 64;
  __shared__ float tile[64][65];
  int t = threadIdx.x;
  int l = t & 15, g = t >> 4;
  const float* xp = x + ((size_t)b * Cq + c0) * Nq + n0;
#pragma unroll
  for (int e = 0; e < 4; e++) {
    int cl = g + e * 16;
    float4 v = *(const float4*)(xp + (size_t)cl * Nq + l * 4);
    tile[cl][l * 4 + 0] = v.x; tile[cl][l * 4 + 1] = v.y;
    tile[cl][l * 4 + 2] = v.z; tile[cl][l * 4 + 3] = v.w;
  }
  __syncthreads();
#pragma unroll
  for (int e = 0; e < 4; e++) {
    int nl = g + e * 16;
    short hi[4], lo[4];
#pragma unroll
    for (int qq = 0; qq < 4; qq++) {
      float v = tile[l * 4 + qq][nl];
      hi[qq] = f2bf(v);
      lo[qq] = f2bf(v - bf2f(hi[qq]));
    }
    size_t off = ((size_t)b * Nq + n0 + nl) * Cq + c0 + l * 4;
    *(short4*)(xthi + off) = make_short4(hi[0], hi[1], hi[2], hi[3]);
    *(short4*)(xtlo + off) = make_short4(lo[0], lo[1], lo[2], lo[3]);
  }
}

// ---------------- K_fg: f,g GEMM -> frag-packed stores ----------------
__global__ __launch_bounds__(512) void k_fg(
    const short* __restrict__ xthi, const short* __restrict__ xtlo,
    const short* __restrict__ whi, const short* __restrict__ wlo,
    const float* __restrict__ bfv, const float* __restrict__ bgv,
    short* __restrict__ ffh, short* __restrict__ ffl,
    short* __restrict__ gfh, short* __restrict__ gfl) {
  int b = blockIdx.y, n0 = blockIdx.x * 64;
  int t = threadIdx.x, w = t >> 6, lane = t & 63, l15 = lane & 15, q = lane >> 4;
  int wr = w & 3, wh = w >> 2;  // row group / o-half (0=f,1=g)
  const short* ah = xthi + ((size_t)b * Nq + n0 + wr * 16 + l15) * Cq;
  const short* al = xtlo + ((size_t)b * Nq + n0 + wr * 16 + l15) * Cq;
  f32x4 z = {0.f, 0.f, 0.f, 0.f};
  f32x4 acc[4] = {z, z, z, z};
  for (int ks = 0; ks < 16; ks++) {
    bf16x8 Ahi = *(const bf16x8*)(ah + ks * 32 + q * 8);
    bf16x8 Alo = *(const bf16x8*)(al + ks * 32 + q * 8);
#pragma unroll
    for (int os = 0; os < 4; os++) {
      int o = wh * 64 + os * 16 + l15;
      bf16x8 Bhi = *(const bf16x8*)(whi + o * 512 + ks * 32 + q * 8);
      bf16x8 Blo = *(const bf16x8*)(wlo + o * 512 + ks * 32 + q * 8);
      acc[os] = MFMA16(Alo, Bhi, acc[os]);
      acc[os] = MFMA16(Ahi, Blo, acc[os]);
      acc[os] = MFMA16(Ahi, Bhi, acc[os]);
    }
  }
#pragma unroll
  for (int os = 0; os < 4; os++) {
#pragma unroll
    for (int r = 0; r < 4; r++) {
      int o = os * 16 + l15;                 // 0..63 within f or g
      int n = n0 + wr * 16 + q * 4 + r;
      float v = acc[os][r] + (wh == 0 ? bfv[o] : bgv[o]);
      size_t off = ((size_t)((b * 256 + (n >> 4)) * 2 + (o >> 5))) * 512
                 + (((o >> 3) & 3) * 16 + (n & 15)) * 8 + (o & 7);
      short h = f2bf(v);
      short lo = f2bf(v - bf2f(h));
      if (wh == 0) { ffh[off] = h; ffl[off] = lo; }
      else         { gfh[off] = h; gfl[off] = lo; }
    }
  }
}

// ---------------- K_stats: partial l_i = sum_j exp(S) over a 1024-j chunk ----
// Writes per-chunk partial sums to lsum4[chunk][b][i] (no atomics).
__global__ __launch_bounds__(512) void k_stats(
    const short* __restrict__ ffh, const short* __restrict__ ffl,
    const short* __restrict__ gfh, const short* __restrict__ gfl,
    float* __restrict__ lsum4) {
  int jch = blockIdx.x, jc = jch * 1024, i0 = blockIdx.y * 64, b = blockIdx.z;
  int t = threadIdx.x, w = t >> 6, lane = t & 63, l15 = lane & 15, q = lane >> 4;
  bf16x8 Ahi[4][2], Alo[4][2];
#pragma unroll
  for (int ig = 0; ig < 4; ig++)
#pragma unroll
    for (int ss = 0; ss < 2; ss++) {
      size_t base = fg_frag(b, (i0 >> 4) + ig, ss) + lane * 8;
      Ahi[ig][ss] = *(const bf16x8*)(ffh + base);
      Alo[ig][ss] = *(const bf16x8*)(ffl + base);
    }
  float ls[16];
#pragma unroll
  for (int a = 0; a < 16; a++) ls[a] = 0.f;
  f32x4 z = {0.f, 0.f, 0.f, 0.f};
  for (int jt = 0; jt < 8; jt++) {
    int tj = (jc >> 4) + w * 8 + jt;
    bf16x8 GBh[2], GBl[2];
#pragma unroll
    for (int ss = 0; ss < 2; ss++) {
      size_t base = fg_frag(b, tj, ss) + lane * 8;
      GBh[ss] = *(const bf16x8*)(gfh + base);
      GBl[ss] = *(const bf16x8*)(gfl + base);
    }
#pragma unroll
    for (int ig = 0; ig < 4; ig++) {
      f32x4 sh = z, sl = z;
#pragma unroll
      for (int ss = 0; ss < 2; ss++) {
        sl = MFMA16(Alo[ig][ss], GBh[ss], sl);
        sl = MFMA16(Ahi[ig][ss], GBl[ss], sl);
        sh = MFMA16(Ahi[ig][ss], GBh[ss], sh);
      }
#pragma unroll
      for (int r = 0; r < 4; r++) ls[ig * 4 + r] += __expf(sh[r] + sl[r]);
    }
  }
#pragma unroll
  for (int m = 1; m < 16; m <<= 1) {
#pragma unroll
    for (int a = 0; a < 16; a++) ls[a] += __shfl_xor(ls[a], m, 64);
  }
  __shared__ float part[8][64];
  if (l15 == 0) {
#pragma unroll
    for (int ig = 0; ig < 4; ig++)
#pragma unroll
      for (int r = 0; r < 4; r++) part[w][ig * 16 + q * 4 + r] = ls[ig * 4 + r];
  }
  __syncthreads();
  if (t < 64) {
    float s = 0.f;
#pragma unroll
    for (int ww = 0; ww < 8; ww++) s += part[ww][t];
    lsum4[(size_t)jch * 16384 + (size_t)b * Nq + i0 + t] = s;
  }
}

// ---------------- K_hv: hvfrag = frag-packed bf16((Wh.x + bh)/l) ----------------
__global__ __launch_bounds__(512) void k_hv(
    const short* __restrict__ whb, const short* __restrict__ xthi,
    const float* __restrict__ bhv, const float* __restrict__ lsum4,
    short* __restrict__ hvf) {
  int si = blockIdx.x, b = blockIdx.y;
  int t = threadIdx.x, w = t >> 6, lane = t & 63, l15 = lane & 15, q = lane >> 4;
  int c0 = w * 64;
  const short* ar0 = xthi + ((size_t)b * Nq + si * 32 + l15) * Cq;
  const short* ar1 = ar0 + 16 * Cq;
  f32x4 z = {0.f, 0.f, 0.f, 0.f};
  f32x4 acc[2][4];
#pragma unroll
  for (int a = 0; a < 2; a++)
#pragma unroll
    for (int c = 0; c < 4; c++) acc[a][c] = z;
  for (int ks = 0; ks < 16; ks++) {
    bf16x8 A0 = *(const bf16x8*)(ar0 + ks * 32 + q * 8);
    bf16x8 A1 = *(const bf16x8*)(ar1 + ks * 32 + q * 8);
#pragma unroll
    for (int ct = 0; ct < 4; ct++) {
      bf16x8 Bv = *(const bf16x8*)(whb + (size_t)(c0 + ct * 16 + l15) * 512 + ks * 32 + q * 8);
      acc[0][ct] = MFMA16(A0, Bv, acc[0][ct]);
      acc[1][ct] = MFMA16(A1, Bv, acc[1][ct]);
    }
  }
  float li[2][4];
#pragma unroll
  for (int it = 0; it < 2; it++)
#pragma unroll
    for (int r = 0; r < 4; r++) {
      size_t idx = (size_t)b * Nq + si * 32 + it * 16 + q * 4 + r;
      float s = lsum4[idx] + lsum4[16384 + idx] + lsum4[32768 + idx] + lsum4[49152 + idx];
      li[it][r] = 1.0f / s;
    }
  int src0 = ((q & 1) << 5) + l15;
  int src1 = src0 + 16;
  int hiSel = q >> 1;
#pragma unroll
  for (int ct = 0; ct < 4; ct++) {
    float bias = bhv[c0 + ct * 16 + l15];
    unsigned u01[2], u23[2];
#pragma unroll
    for (int it = 0; it < 2; it++) {
      float v0 = (acc[it][ct][0] + bias) * li[it][0];
      float v1 = (acc[it][ct][1] + bias) * li[it][1];
      float v2 = (acc[it][ct][2] + bias) * li[it][2];
      float v3 = (acc[it][ct][3] + bias) * li[it][3];
      u01[it] = (unsigned)(unsigned short)f2bf(v0) | ((unsigned)(unsigned short)f2bf(v1) << 16);
      u23[it] = (unsigned)(unsigned short)f2bf(v2) | ((unsigned)(unsigned short)f2bf(v3) << 16);
    }
    unsigned a0 = __shfl((int)u01[0], src0), b0 = __shfl((int)u01[1], src0);
    unsigned a1 = __shfl((int)u23[0], src0), b1 = __shfl((int)u23[1], src0);
    unsigned a2 = __shfl((int)u01[0], src1), b2 = __shfl((int)u01[1], src1);
    unsigned a3 = __shfl((int)u23[0], src1), b3 = __shfl((int)u23[1], src1);
    uint4 st;
    st.x = hiSel ? b0 : a0;
    st.y = hiSel ? b1 : a1;
    st.z = hiSel ? b2 : a2;
    st.w = hiSel ? b3 : a3;
    *(uint4*)(hvf + hv_frag(b, (c0 >> 4) + ct, si) + (size_t)lane * 8) = st;
  }
}

// ---------------- K_zero: out = 0 (epilogue atomics accumulate into it) ----
__global__ __launch_bounds__(256) void k_zero(float* __restrict__ out) {
  int gid = blockIdx.x * 256 + threadIdx.x;   // 262144 threads
  float4 z4 = {0.f, 0.f, 0.f, 0.f};
#pragma unroll
  for (int k = 0; k < 8; k++)
    *(float4*)(out + ((size_t)(k * 262144 + gid)) * 4) = z4;
}

// ---------------- K_attn: out += gamma * hv2 @ exp(S) (+ x) ----------------
// 512 blocks = (b 4) x (ipar 2) x (jt64 64); combo = L&7 = (b,ipar) -> XCD
// (hvf-half 2MB + ff 0.5MB L2-resident). 512 thr, 2 blocks/CU = 4 waves/SIMD
// (launch_bounds(512,4) caps VGPR 128). Block processes i-chunks
// it = ipar*32 + k, k=0..31. Loop body identical to R9 (verified):
//   issue FF(next) + HV(cur) -> regs (in flight across barrier)
//   lgkmcnt(0)-only drain; s_barrier
//   computeS(next) -> pt[1-buf]; doPV(cur) from pt[buf]
// Epilogue: atomicAdd(out, gamma*acc [+ x if ipar==0]); out pre-zeroed by
// k_zero; exactly 2 commutative f32 adds per address -> deterministic.
__global__ __launch_bounds__(512, 4) void k_attn(
    const short* __restrict__ ffh, const short* __restrict__ ffl,
    const short* __restrict__ gfh, const short* __restrict__ gfl,
    const short* __restrict__ hvf, const float* __restrict__ x,
    const float* __restrict__ gp, float* __restrict__ out) {
  int L = blockIdx.x;
  int combo = L & 7;                      // -> XCD id under round-robin dispatch
  int b = combo >> 1, ipar = combo & 1;   // batch, i-half
  int jt64 = L >> 3;                      // 0..63
  int j0 = jt64 * 64;
  int it0 = ipar * 32;                    // this block's first i-chunk
  int t = threadIdx.x, w = t >> 6, lane = t & 63, l15 = lane & 15, q = lane >> 4;
  int iq = w & 3, jh = w >> 2;            // S roles
  __shared__ __align__(16) short pt[2][64 * PSTR];   // 18.4 KB
  float gamma = gp[0];
  f32x4 z = {0.f, 0.f, 0.f, 0.f};
  f32x4 acc[4][4];                        // [ct][jt]
#pragma unroll
  for (int a = 0; a < 4; a++)
#pragma unroll
    for (int bb = 0; bb < 4; bb++) acc[a][bb] = z;
  // Hoist g frags for this wave's S j-half (2 tiles of 16 j).
  bf16x8 GBh[2][2], GBl[2][2];
#pragma unroll
  for (int jt = 0; jt < 2; jt++)
#pragma unroll
    for (int ss = 0; ss < 2; ss++) {
      size_t base = fg_frag(b, (j0 >> 4) + jh * 2 + jt, ss) + lane * 8;
      GBh[jt][ss] = *(const bf16x8*)(gfh + base);
      GBl[jt][ss] = *(const bf16x8*)(gfl + base);
    }

  // S compute from pre-loaded register fragments.
  auto computeS = [&](const bf16x8* Ah, const bf16x8* Al, int buf) {
#pragma unroll
    for (int jt = 0; jt < 2; jt++) {
      f32x4 sh = z, sl = z;
#pragma unroll
      for (int ss = 0; ss < 2; ss++) {
        sl = MFMA16(Al[ss], GBh[jt][ss], sl);
        sl = MFMA16(Ah[ss], GBl[jt][ss], sl);
        sh = MFMA16(Ah[ss], GBh[jt][ss], sh);
      }
      unsigned p01 = (unsigned)(unsigned short)f2bf(__expf(sh[0] + sl[0])) |
                     ((unsigned)(unsigned short)f2bf(__expf(sh[1] + sl[1])) << 16);
      unsigned p23 = (unsigned)(unsigned short)f2bf(__expf(sh[2] + sl[2])) |
                     ((unsigned)(unsigned short)f2bf(__expf(sh[3] + sl[3])) << 16);
      uint2 pv; pv.x = p01; pv.y = p23;
      *(uint2*)(&pt[buf][(jh * 32 + jt * 16 + l15) * PSTR + iq * 16 + q * 4]) = pv;
    }
  };
  auto loadFF = [&](int n, bf16x8* Dh, bf16x8* Dl) {
#pragma unroll
    for (int ss = 0; ss < 2; ss++) {
      size_t base = fg_frag(b, n * 4 + iq, ss) + lane * 8;
      Dh[ss] = *(const bf16x8*)(ffh + base);
      Dl[ss] = *(const bf16x8*)(ffl + base);
    }
  };

  bf16x8 FFh[2], FFl[2];
  // Prologue: load ff(it0), compute pt[0].
  loadFF(it0, FFh, FFl);
  computeS(FFh, FFl, 0);

  for (int k = 0; k < 32; k++) {
    int it = it0 + k;
    int buf = k & 1;
    // --- pre-barrier VMEM issue (in flight across the barrier) ---
    if (k < 31) loadFF(it + 1, FFh, FFl);
    bf16x8 HV[2][4];
#pragma unroll
    for (int ss = 0; ss < 2; ss++)
#pragma unroll
      for (int ct = 0; ct < 4; ct++) {
        size_t hb = hv_frag(b, w * 4 + ct, it * 2 + ss) + lane * 8;
        HV[ss][ct] = *(const bf16x8*)(hvf + hb);
      }
    // --- barrier: drain LDS writes only; leave VMEM in flight ---
    asm volatile("s_waitcnt lgkmcnt(0)" ::: "memory");
    __builtin_amdgcn_s_barrier();
    asm volatile("" ::: "memory");
    // --- post-barrier: S(it+1) then PV(it) ---
    if (k < 31) computeS(FFh, FFl, 1 - buf);
#pragma unroll
    for (int ss = 0; ss < 2; ss++) {
      bf16x8 PB[4];
#pragma unroll
      for (int jt = 0; jt < 4; jt++)
        PB[jt] = *(const bf16x8*)(&pt[buf][(jt * 16 + l15) * PSTR + ss * 32 + q * 8]);
#pragma unroll
      for (int ct = 0; ct < 4; ct++) {
#pragma unroll
        for (int jt = 0; jt < 4; jt++)
          acc[ct][jt] = MFMA16(HV[ss][ct], PB[jt], acc[ct][jt]);
      }
    }
  }
#pragma unroll
  for (int ct = 0; ct < 4; ct++) {
#pragma unroll
    for (int jt = 0; jt < 4; jt++) {
#pragma unroll
      for (int r = 0; r < 4; r++) {
        int c = w * 64 + ct * 16 + q * 4 + r;
        int j = j0 + jt * 16 + l15;
        size_t off = ((size_t)b * Cq + c) * Nq + j;
        float v = gamma * acc[ct][jt][r];
        if (ipar == 0) v += x[off];
        atomicAdd(&out[off], v);
      }
    }
  }
}

extern "C" void kernel_launch(void* const* d_in, const int* in_sizes, int n_in,
                              void* d_out, int out_size, void* d_ws, size_t ws_size,
                              hipStream_t stream) {
  (void)in_sizes; (void)n_in; (void)out_size; (void)ws_size;
  const float* x  = (const float*)d_in[0];
  const float* Wf = (const float*)d_in[1];
  const float* bf = (const float*)d_in[2];
  const float* Wg = (const float*)d_in[3];
  const float* bg = (const float*)d_in[4];
  const float* Wh = (const float*)d_in[5];
  const float* bh = (const float*)d_in[6];
  const float* gm = (const float*)d_in[7];
  float* out = (float*)d_out;
  char* ws = (char*)d_ws;
  // Workspace layout (bytes); total 59,768,832 (~57 MB)
  short* xthi  = (short*)(ws);               // 16,777,216  (B,N,C) bf16 hi
  short* xtlo  = (short*)(ws + 16777216);    // 16,777,216  lo
  short* ffh   = (short*)(ws + 33554432);    //  2,097,152  f frag-packed hi
  short* ffl   = (short*)(ws + 35651584);    //  2,097,152  f lo
  short* gfh   = (short*)(ws + 37748736);    //  2,097,152  g frag-packed hi
  short* gfl   = (short*)(ws + 39845888);    //  2,097,152  g lo
  short* whi   = (short*)(ws + 41943040);    //    131,072  (128,512)
  short* wlo   = (short*)(ws + 42074112);    //    131,072
  short* whb   = (short*)(ws + 42205184);    //    524,288  (512,512)
  float* lsum4 = (float*)(ws + 42729472);    //    262,144  (4 chunks, B, N)
  short* hvf   = (short*)(ws + 42991616);    // 16,777,216  hv frag-packed bf16

  hipLaunchKernelGGL(k_prepw, dim3(1024), dim3(256), 0, stream, Wf, Wg, Wh, whi, wlo, whb);
  hipLaunchKernelGGL(k_xpose, dim3(64, 8, 4), dim3(256), 0, stream, x, xthi, xtlo);
  hipLaunchKernelGGL(k_fg, dim3(64, 4), dim3(512), 0, stream,
                     xthi, xtlo, whi, wlo, bf, bg, ffh, ffl, gfh, gfl);
  hipLaunchKernelGGL(k_stats, dim3(4, 64, 4), dim3(512), 0, stream, ffh, ffl, gfh, gfl, lsum4);
  hipLaunchKernelGGL(k_hv, dim3(128, 4), dim3(512), 0, stream, whb, xthi, bh, lsum4, hvf);
  hipLaunchKernelGGL(k_zero, dim3(1024), dim3(256), 0, stream, out);
  hipLaunchKernelGGL(k_attn, dim3(512), dim3(512), 0, stream,
                     ffh, ffl, gfh, gfl, hvf, x, gm, out);
}

// Round 7
// 325.792 us; speedup vs baseline: 1.4563x; 1.4563x over previous
//
#include <hip/hip_runtime.h>

// self_attention: B=4, C=512, C8=64, N=64*64=4096
// R13: materialize P = exp(S) (bf16, frag-packed) in k_stats; replace k_attn
// with barrier-free pure-GEMM k_pv. R6-R12 ledger: the barrier-lockstep
// S-recompute structure peaked at 105.5us (R9); every TLP/traffic fix inside
// it failed (R7 dup-VMEM, R8 2xS, R11 depth-2 null, R12 atomics disaster).
// k_stats already computes every exp(S) for lsum -> also store P^T in the
// exact MFMA B-frag layout PV consumes (identical bf16 values to old pt).
// k_pv: out[c,j] = sum_i hv2[c,i] P^T[i,j]: 6 loads + 8 MFMA/iter, no LDS,
// no barrier, compiler pipelines freely. Tiling now free: grid 512 =
// (b x c-half x j64); combo=L&7 -> XCD pins hvf-half 2MB in L2; 2 blocks/CU
// = 4 waves/SIMD, zero duplicated VMEM, disjoint stores (no atomics).
// Risk: P needs 134MB -> ws total ~194MB.

#define Bq 4
#define Cq 512
#define Nq 4096

typedef __attribute__((ext_vector_type(8))) short bf16x8;
typedef __attribute__((ext_vector_type(4))) float f32x4;

__device__ __forceinline__ short f2bf(float f) {
  unsigned u = __float_as_uint(f);
  u += 0x7fffu + ((u >> 16) & 1u);   // RNE
  return (short)(u >> 16);
}
__device__ __forceinline__ float bf2f(short h) {
  return __uint_as_float(((unsigned)(unsigned short)h) << 16);
}

#define MFMA16(A, B, C) __builtin_amdgcn_mfma_f32_16x16x32_bf16((A), (B), (C), 0, 0, 0)

// frag base (in shorts) for f/g token-tile t16 (16 tokens), k-chunk ss (32 of 64)
__device__ __forceinline__ size_t fg_frag(int b, int t16, int ss) {
  return ((size_t)((b * 256 + t16) * 2 + ss)) * 512;
}
// frag base for hv c-tile tc (16 c), i-chunk si (32 of 4096)
__device__ __forceinline__ size_t hv_frag(int b, int tc, int si) {
  return ((size_t)((b * 32 + tc) * 128 + si)) * 512;
}
// frag base for P^T j-tile jt16 (16 j), i-chunk si (32 of 4096).
// Element P^T[j][i]: offset ((i32>>3)*16 + j)*8 + (i32&7); lane*8 read gives
// B-frag col=j(=lane&15), k=i=(lane>>4)*8+e -- the layout PV's MFMA needs.
__device__ __forceinline__ size_t p_frag(int b, int jt16, int si) {
  return ((size_t)((b * 256 + jt16) * 128 + si)) * 512;
}

// ---------------- K_prepw: W splits ----------------
__global__ __launch_bounds__(256) void k_prepw(
    const float* __restrict__ Wf, const float* __restrict__ Wg,
    const float* __restrict__ Wh,
    short* __restrict__ whi, short* __restrict__ wlo, short* __restrict__ whb) {
  int gid = blockIdx.x * 256 + threadIdx.x;  // 0..262143
  if (gid < 128 * 512) {
    int row = gid >> 9;
    float v = (row < 64) ? Wf[gid] : Wg[gid - 32768];
    short h = f2bf(v);
    whi[gid] = h;
    wlo[gid] = f2bf(v - bf2f(h));
  }
  whb[gid] = f2bf(Wh[gid]);
}

// ---------------- K_xpose: x (B,C,N) fp32 -> XT (B,N,C) bf16 hi/lo ----------------
__global__ __launch_bounds__(256) void k_xpose(
    const float* __restrict__ x, short* __restrict__ xthi, short* __restrict__ xtlo) {
  int b = blockIdx.z, c0 = blockIdx.y * 64, n0 = blockIdx.x * 64;
  __shared__ float tile[64][65];
  int t = threadIdx.x;
  int l = t & 15, g = t >> 4;
  const float* xp = x + ((size_t)b * Cq + c0) * Nq + n0;
#pragma unroll
  for (int e = 0; e < 4; e++) {
    int cl = g + e * 16;
    float4 v = *(const float4*)(xp + (size_t)cl * Nq + l * 4);
    tile[cl][l * 4 + 0] = v.x; tile[cl][l * 4 + 1] = v.y;
    tile[cl][l * 4 + 2] = v.z; tile[cl][l * 4 + 3] = v.w;
  }
  __syncthreads();
#pragma unroll
  for (int e = 0; e < 4; e++) {
    int nl = g + e * 16;
    short hi[4], lo[4];
#pragma unroll
    for (int qq = 0; qq < 4; qq++) {
      float v = tile[l * 4 + qq][nl];
      hi[qq] = f2bf(v);
      lo[qq] = f2bf(v - bf2f(hi[qq]));
    }
    size_t off = ((size_t)b * Nq + n0 + nl) * Cq + c0 + l * 4;
    *(short4*)(xthi + off) = make_short4(hi[0], hi[1], hi[2], hi[3]);
    *(short4*)(xtlo + off) = make_short4(lo[0], lo[1], lo[2], lo[3]);
  }
}

// ---------------- K_fg: f,g GEMM -> frag-packed stores ----------------
__global__ __launch_bounds__(512) void k_fg(
    const short* __restrict__ xthi, const short* __restrict__ xtlo,
    const short* __restrict__ whi, const short* __restrict__ wlo,
    const float* __restrict__ bfv, const float* __restrict__ bgv,
    short* __restrict__ ffh, short* __restrict__ ffl,
    short* __restrict__ gfh, short* __restrict__ gfl) {
  int b = blockIdx.y, n0 = blockIdx.x * 64;
  int t = threadIdx.x, w = t >> 6, lane = t & 63, l15 = lane & 15, q = lane >> 4;
  int wr = w & 3, wh = w >> 2;  // row group / o-half (0=f,1=g)
  const short* ah = xthi + ((size_t)b * Nq + n0 + wr * 16 + l15) * Cq;
  const short* al = xtlo + ((size_t)b * Nq + n0 + wr * 16 + l15) * Cq;
  f32x4 z = {0.f, 0.f, 0.f, 0.f};
  f32x4 acc[4] = {z, z, z, z};
  for (int ks = 0; ks < 16; ks++) {
    bf16x8 Ahi = *(const bf16x8*)(ah + ks * 32 + q * 8);
    bf16x8 Alo = *(const bf16x8*)(al + ks * 32 + q * 8);
#pragma unroll
    for (int os = 0; os < 4; os++) {
      int o = wh * 64 + os * 16 + l15;
      bf16x8 Bhi = *(const bf16x8*)(whi + o * 512 + ks * 32 + q * 8);
      bf16x8 Blo = *(const bf16x8*)(wlo + o * 512 + ks * 32 + q * 8);
      acc[os] = MFMA16(Alo, Bhi, acc[os]);
      acc[os] = MFMA16(Ahi, Blo, acc[os]);
      acc[os] = MFMA16(Ahi, Bhi, acc[os]);
    }
  }
#pragma unroll
  for (int os = 0; os < 4; os++) {
#pragma unroll
    for (int r = 0; r < 4; r++) {
      int o = os * 16 + l15;                 // 0..63 within f or g
      int n = n0 + wr * 16 + q * 4 + r;
      float v = acc[os][r] + (wh == 0 ? bfv[o] : bgv[o]);
      size_t off = ((size_t)((b * 256 + (n >> 4)) * 2 + (o >> 5))) * 512
                 + (((o >> 3) & 3) * 16 + (n & 15)) * 8 + (o & 7);
      short h = f2bf(v);
      short lo = f2bf(v - bf2f(h));
      if (wh == 0) { ffh[off] = h; ffl[off] = lo; }
      else         { gfh[off] = h; gfl[off] = lo; }
    }
  }
}

// ---------------- K_stats: l_i partials + P^T = bf16(exp(S)) frag-packed ----
// Block (jch 1024 j's, i0 64 i's, b). Lane holds S[i=q*4+r (per ig), j=l15]
// per 16-j tile tj. Writes: lsum4 partials (as before) and P^T frags.
__global__ __launch_bounds__(512) void k_stats(
    const short* __restrict__ ffh, const short* __restrict__ ffl,
    const short* __restrict__ gfh, const short* __restrict__ gfl,
    float* __restrict__ lsum4, short* __restrict__ pmat) {
  int jch = blockIdx.x, jc = jch * 1024, i0 = blockIdx.y * 64, b = blockIdx.z;
  int t = threadIdx.x, w = t >> 6, lane = t & 63, l15 = lane & 15, q = lane >> 4;
  bf16x8 Ahi[4][2], Alo[4][2];
#pragma unroll
  for (int ig = 0; ig < 4; ig++)
#pragma unroll
    for (int ss = 0; ss < 2; ss++) {
      size_t base = fg_frag(b, (i0 >> 4) + ig, ss) + lane * 8;
      Ahi[ig][ss] = *(const bf16x8*)(ffh + base);
      Alo[ig][ss] = *(const bf16x8*)(ffl + base);
    }
  float ls[16];
#pragma unroll
  for (int a = 0; a < 16; a++) ls[a] = 0.f;
  f32x4 z = {0.f, 0.f, 0.f, 0.f};
  for (int jt = 0; jt < 8; jt++) {
    int tj = (jc >> 4) + w * 8 + jt;
    bf16x8 GBh[2], GBl[2];
#pragma unroll
    for (int ss = 0; ss < 2; ss++) {
      size_t base = fg_frag(b, tj, ss) + lane * 8;
      GBh[ss] = *(const bf16x8*)(gfh + base);
      GBl[ss] = *(const bf16x8*)(gfl + base);
    }
#pragma unroll
    for (int ig = 0; ig < 4; ig++) {
      f32x4 sh = z, sl = z;
#pragma unroll
      for (int ss = 0; ss < 2; ss++) {
        sl = MFMA16(Alo[ig][ss], GBh[ss], sl);
        sl = MFMA16(Ahi[ig][ss], GBl[ss], sl);
        sh = MFMA16(Ahi[ig][ss], GBh[ss], sh);
      }
      float ev[4];
#pragma unroll
      for (int r = 0; r < 4; r++) {
        ev[r] = __expf(sh[r] + sl[r]);
        ls[ig * 4 + r] += ev[r];
      }
      // P^T write: i (block-local) = ig*16 + q*4 + r -> si = i0/32 + (ig>>1),
      // i32 = (ig&1)*16 + q*4 + r; r=0..3 contiguous shorts -> one uint2.
      uint2 pv;
      pv.x = (unsigned)(unsigned short)f2bf(ev[0]) |
             ((unsigned)(unsigned short)f2bf(ev[1]) << 16);
      pv.y = (unsigned)(unsigned short)f2bf(ev[2]) |
             ((unsigned)(unsigned short)f2bf(ev[3]) << 16);
      size_t pb = p_frag(b, tj, (i0 >> 5) + (ig >> 1)) +
                  (size_t)(((ig & 1) * 2 + (q >> 1)) * 128 + l15 * 8 + (q & 1) * 4);
      *(uint2*)(pmat + pb) = pv;
    }
  }
#pragma unroll
  for (int m = 1; m < 16; m <<= 1) {
#pragma unroll
    for (int a = 0; a < 16; a++) ls[a] += __shfl_xor(ls[a], m, 64);
  }
  __shared__ float part[8][64];
  if (l15 == 0) {
#pragma unroll
    for (int ig = 0; ig < 4; ig++)
#pragma unroll
      for (int r = 0; r < 4; r++) part[w][ig * 16 + q * 4 + r] = ls[ig * 4 + r];
  }
  __syncthreads();
  if (t < 64) {
    float s = 0.f;
#pragma unroll
    for (int ww = 0; ww < 8; ww++) s += part[ww][t];
    lsum4[(size_t)jch * 16384 + (size_t)b * Nq + i0 + t] = s;
  }
}

// ---------------- K_hv: hvfrag = frag-packed bf16((Wh.x + bh)/l) ----------------
__global__ __launch_bounds__(512) void k_hv(
    const short* __restrict__ whb, const short* __restrict__ xthi,
    const float* __restrict__ bhv, const float* __restrict__ lsum4,
    short* __restrict__ hvf) {
  int si = blockIdx.x, b = blockIdx.y;
  int t = threadIdx.x, w = t >> 6, lane = t & 63, l15 = lane & 15, q = lane >> 4;
  int c0 = w * 64;
  const short* ar0 = xthi + ((size_t)b * Nq + si * 32 + l15) * Cq;
  const short* ar1 = ar0 + 16 * Cq;
  f32x4 z = {0.f, 0.f, 0.f, 0.f};
  f32x4 acc[2][4];
#pragma unroll
  for (int a = 0; a < 2; a++)
#pragma unroll
    for (int c = 0; c < 4; c++) acc[a][c] = z;
  for (int ks = 0; ks < 16; ks++) {
    bf16x8 A0 = *(const bf16x8*)(ar0 + ks * 32 + q * 8);
    bf16x8 A1 = *(const bf16x8*)(ar1 + ks * 32 + q * 8);
#pragma unroll
    for (int ct = 0; ct < 4; ct++) {
      bf16x8 Bv = *(const bf16x8*)(whb + (size_t)(c0 + ct * 16 + l15) * 512 + ks * 32 + q * 8);
      acc[0][ct] = MFMA16(A0, Bv, acc[0][ct]);
      acc[1][ct] = MFMA16(A1, Bv, acc[1][ct]);
    }
  }
  float li[2][4];
#pragma unroll
  for (int it = 0; it < 2; it++)
#pragma unroll
    for (int r = 0; r < 4; r++) {
      size_t idx = (size_t)b * Nq + si * 32 + it * 16 + q * 4 + r;
      float s = lsum4[idx] + lsum4[16384 + idx] + lsum4[32768 + idx] + lsum4[49152 + idx];
      li[it][r] = 1.0f / s;
    }
  int src0 = ((q & 1) << 5) + l15;
  int src1 = src0 + 16;
  int hiSel = q >> 1;
#pragma unroll
  for (int ct = 0; ct < 4; ct++) {
    float bias = bhv[c0 + ct * 16 + l15];
    unsigned u01[2], u23[2];
#pragma unroll
    for (int it = 0; it < 2; it++) {
      float v0 = (acc[it][ct][0] + bias) * li[it][0];
      float v1 = (acc[it][ct][1] + bias) * li[it][1];
      float v2 = (acc[it][ct][2] + bias) * li[it][2];
      float v3 = (acc[it][ct][3] + bias) * li[it][3];
      u01[it] = (unsigned)(unsigned short)f2bf(v0) | ((unsigned)(unsigned short)f2bf(v1) << 16);
      u23[it] = (unsigned)(unsigned short)f2bf(v2) | ((unsigned)(unsigned short)f2bf(v3) << 16);
    }
    unsigned a0 = __shfl((int)u01[0], src0), b0 = __shfl((int)u01[1], src0);
    unsigned a1 = __shfl((int)u23[0], src0), b1 = __shfl((int)u23[1], src0);
    unsigned a2 = __shfl((int)u01[0], src1), b2 = __shfl((int)u01[1], src1);
    unsigned a3 = __shfl((int)u23[0], src1), b3 = __shfl((int)u23[1], src1);
    uint4 st;
    st.x = hiSel ? b0 : a0;
    st.y = hiSel ? b1 : a1;
    st.z = hiSel ? b2 : a2;
    st.w = hiSel ? b3 : a3;
    *(uint4*)(hvf + hv_frag(b, (c0 >> 4) + ct, si) + (size_t)lane * 8) = st;
  }
}

// ---------------- K_pv: out = gamma * hv2 @ P + x (pure GEMM) ----------------
// Grid 512 = (b 4) x (ch 2) x (jt64 64); combo = L&7 = (b,ch) -> XCD
// (hvf-half 2MB L2-resident). 512 thr = 8 waves, 2 blocks/CU = 4 waves/SIMD
// (launch_bounds(512,4) caps VGPR 128). Wave = (cg = w&3: 64-c strip within
// the 256-c half) x (jg = w>>2: 32-j half of the 64-j tile). No LDS, no
// barrier: 6 loads + 8 MFMA per i-chunk, compiler software-pipelines.
// Accumulation over si ascending == old ss-order -> bitwise-identical sums.
__global__ __launch_bounds__(512, 4) void k_pv(
    const short* __restrict__ hvf, const short* __restrict__ pmat,
    const float* __restrict__ x, const float* __restrict__ gp,
    float* __restrict__ out) {
  int L = blockIdx.x;
  int combo = L & 7;                      // -> XCD id under round-robin dispatch
  int b = combo >> 1, ch = combo & 1;     // batch, c-half
  int jt64 = L >> 3;                      // 0..63
  int j0 = jt64 * 64;
  int t = threadIdx.x, w = t >> 6, lane = t & 63, l15 = lane & 15, q = lane >> 4;
  int cg = w & 3, jg = w >> 2;            // c-strip, j-half
  float gamma = gp[0];
  f32x4 z = {0.f, 0.f, 0.f, 0.f};
  f32x4 acc[4][2];                        // [ct][jt]
#pragma unroll
  for (int a = 0; a < 4; a++)
#pragma unroll
    for (int bb = 0; bb < 2; bb++) acc[a][bb] = z;
  const short* hbase = hvf + (size_t)lane * 8;
  const short* pbase = pmat + (size_t)lane * 8;
  int tc0 = ch * 16 + cg * 4;             // first hv c-tile
  int jp0 = (j0 >> 4) + jg * 2;           // first P j-tile
#pragma unroll 2
  for (int si = 0; si < 128; si++) {
    bf16x8 HV[4], PB[2];
#pragma unroll
    for (int ct = 0; ct < 4; ct++)
      HV[ct] = *(const bf16x8*)(hbase + hv_frag(b, tc0 + ct, si));
#pragma unroll
    for (int jt = 0; jt < 2; jt++)
      PB[jt] = *(const bf16x8*)(pbase + p_frag(b, jp0 + jt, si));
#pragma unroll
    for (int ct = 0; ct < 4; ct++)
#pragma unroll
      for (int jt = 0; jt < 2; jt++)
        acc[ct][jt] = MFMA16(HV[ct], PB[jt], acc[ct][jt]);
  }
#pragma unroll
  for (int ct = 0; ct < 4; ct++) {
#pragma unroll
    for (int jt = 0; jt < 2; jt++) {
#pragma unroll
      for (int r = 0; r < 4; r++) {
        int c = ch * 256 + cg * 64 + ct * 16 + q * 4 + r;
        int j = j0 + jg * 32 + jt * 16 + l15;
        size_t off = ((size_t)b * Cq + c) * Nq + j;
        out[off] = gamma * acc[ct][jt][r] + x[off];
      }
    }
  }
}

extern "C" void kernel_launch(void* const* d_in, const int* in_sizes, int n_in,
                              void* d_out, int out_size, void* d_ws, size_t ws_size,
                              hipStream_t stream) {
  (void)in_sizes; (void)n_in; (void)out_size; (void)ws_size;
  const float* x  = (const float*)d_in[0];
  const float* Wf = (const float*)d_in[1];
  const float* bf = (const float*)d_in[2];
  const float* Wg = (const float*)d_in[3];
  const float* bg = (const float*)d_in[4];
  const float* Wh = (const float*)d_in[5];
  const float* bh = (const float*)d_in[6];
  const float* gm = (const float*)d_in[7];
  float* out = (float*)d_out;
  char* ws = (char*)d_ws;
  // Workspace layout (bytes); total 193,986,560 (~185 MB)
  short* xthi  = (short*)(ws);               // 16,777,216  (B,N,C) bf16 hi
  short* xtlo  = (short*)(ws + 16777216);    // 16,777,216  lo
  short* ffh   = (short*)(ws + 33554432);    //  2,097,152  f frag-packed hi
  short* ffl   = (short*)(ws + 35651584);    //  2,097,152  f lo
  short* gfh   = (short*)(ws + 37748736);    //  2,097,152  g frag-packed hi
  short* gfl   = (short*)(ws + 39845888);    //  2,097,152  g lo
  short* whi   = (short*)(ws + 41943040);    //    131,072  (128,512)
  short* wlo   = (short*)(ws + 42074112);    //    131,072
  short* whb   = (short*)(ws + 42205184);    //    524,288  (512,512)
  float* lsum4 = (float*)(ws + 42729472);    //    262,144  (4 chunks, B, N)
  short* hvf   = (short*)(ws + 42991616);    // 16,777,216  hv frag-packed bf16
  short* pmat  = (short*)(ws + 59768832);    // 134,217,728 P^T frag-packed bf16

  hipLaunchKernelGGL(k_prepw, dim3(1024), dim3(256), 0, stream, Wf, Wg, Wh, whi, wlo, whb);
  hipLaunchKernelGGL(k_xpose, dim3(64, 8, 4), dim3(256), 0, stream, x, xthi, xtlo);
  hipLaunchKernelGGL(k_fg, dim3(64, 4), dim3(512), 0, stream,
                     xthi, xtlo, whi, wlo, bf, bg, ffh, ffl, gfh, gfl);
  hipLaunchKernelGGL(k_stats, dim3(4, 64, 4), dim3(512), 0, stream,
                     ffh, ffl, gfh, gfl, lsum4, pmat);
  hipLaunchKernelGGL(k_hv, dim3(128, 4), dim3(512), 0, stream, whb, xthi, bh, lsum4, hvf);
  hipLaunchKernelGGL(k_pv, dim3(512), dim3(512), 0, stream, hvf, pmat, x, gm, out);
}

// Round 9
// 290.234 us; speedup vs baseline: 1.6347x; 1.1225x over previous
//
#include <hip/hip_runtime.h>

// self_attention: B=4, C=512, C8=64, N=64*64=4096
// R15: R14's LDS-staged k_pv with LDS cut 96KB -> 48KB (static __shared__
// >64KB = sharedMemPerBlock is the prime suspect for R14's container-level
// failure; schedule logic audited clean). Theory unchanged from R14:
// R13's barrier-free k_pv issued 3.07GB VMEM (HV 2x + P 4x in-block dup)
// = 25.7 TB/s ~ L2 ceiling -> delivery-bound 119.5us. Fix: share operands
// via LDS. Grid 256 = (b4 x ch2 x j128 32); combo=L&7 -> XCD. 512 thr,
// wave = (cg=w&3: 64c) x (jg=w>>2: 64j), acc[4][4]. Stage ONE si/step:
// 24 tiles x 1KB, dbuf -> lds[2][24][512] = 48KB. 3 gload_lds(16B)/wave/step,
// counted vmcnt(3) (never 0 mid-loop, T4), 2 raw barriers/step, 128 steps:
//   STAGE(k+1); vmcnt(3) [drains k]; barrier; COMPUTE(k); lgkm(0); barrier
// LDS linear = global layout -> MFMA inputs bitwise == R13-verified k_pv;
// si ascending, 1 MFMA/acc/si -> identical accumulation order.

#define Bq 4
#define Cq 512
#define Nq 4096

typedef __attribute__((ext_vector_type(8))) short bf16x8;
typedef __attribute__((ext_vector_type(4))) float f32x4;

__device__ __forceinline__ short f2bf(float f) {
  unsigned u = __float_as_uint(f);
  u += 0x7fffu + ((u >> 16) & 1u);   // RNE
  return (short)(u >> 16);
}
__device__ __forceinline__ float bf2f(short h) {
  return __uint_as_float(((unsigned)(unsigned short)h) << 16);
}

#define MFMA16(A, B, C) __builtin_amdgcn_mfma_f32_16x16x32_bf16((A), (B), (C), 0, 0, 0)

typedef __attribute__((address_space(1))) const void gas_void;
typedef __attribute__((address_space(3))) void las_void;
__device__ __forceinline__ void gl_lds16(const short* g, short* l) {
  __builtin_amdgcn_global_load_lds((gas_void*)g, (las_void*)l, 16, 0, 0);
}

// frag base (in shorts) for f/g token-tile t16 (16 tokens), k-chunk ss (32 of 64)
__device__ __forceinline__ size_t fg_frag(int b, int t16, int ss) {
  return ((size_t)((b * 256 + t16) * 2 + ss)) * 512;
}
// frag base for hv c-tile tc (16 c), i-chunk si (32 of 4096)
__device__ __forceinline__ size_t hv_frag(int b, int tc, int si) {
  return ((size_t)((b * 32 + tc) * 128 + si)) * 512;
}
// frag base for P^T j-tile jt16 (16 j), i-chunk si (32 of 4096)
__device__ __forceinline__ size_t p_frag(int b, int jt16, int si) {
  return ((size_t)((b * 256 + jt16) * 128 + si)) * 512;
}

// ---------------- K_prepw: W splits ----------------
__global__ __launch_bounds__(256) void k_prepw(
    const float* __restrict__ Wf, const float* __restrict__ Wg,
    const float* __restrict__ Wh,
    short* __restrict__ whi, short* __restrict__ wlo, short* __restrict__ whb) {
  int gid = blockIdx.x * 256 + threadIdx.x;  // 0..262143
  if (gid < 128 * 512) {
    int row = gid >> 9;
    float v = (row < 64) ? Wf[gid] : Wg[gid - 32768];
    short h = f2bf(v);
    whi[gid] = h;
    wlo[gid] = f2bf(v - bf2f(h));
  }
  whb[gid] = f2bf(Wh[gid]);
}

// ---------------- K_xpose: x (B,C,N) fp32 -> XT (B,N,C) bf16 hi/lo ----------------
__global__ __launch_bounds__(256) void k_xpose(
    const float* __restrict__ x, short* __restrict__ xthi, short* __restrict__ xtlo) {
  int b = blockIdx.z, c0 = blockIdx.y * 64, n0 = blockIdx.x * 64;
  __shared__ float tile[64][65];
  int t = threadIdx.x;
  int l = t & 15, g = t >> 4;
  const float* xp = x + ((size_t)b * Cq + c0) * Nq + n0;
#pragma unroll
  for (int e = 0; e < 4; e++) {
    int cl = g + e * 16;
    float4 v = *(const float4*)(xp + (size_t)cl * Nq + l * 4);
    tile[cl][l * 4 + 0] = v.x; tile[cl][l * 4 + 1] = v.y;
    tile[cl][l * 4 + 2] = v.z; tile[cl][l * 4 + 3] = v.w;
  }
  __syncthreads();
#pragma unroll
  for (int e = 0; e < 4; e++) {
    int nl = g + e * 16;
    short hi[4], lo[4];
#pragma unroll
    for (int qq = 0; qq < 4; qq++) {
      float v = tile[l * 4 + qq][nl];
      hi[qq] = f2bf(v);
      lo[qq] = f2bf(v - bf2f(hi[qq]));
    }
    size_t off = ((size_t)b * Nq + n0 + nl) * Cq + c0 + l * 4;
    *(short4*)(xthi + off) = make_short4(hi[0], hi[1], hi[2], hi[3]);
    *(short4*)(xtlo + off) = make_short4(lo[0], lo[1], lo[2], lo[3]);
  }
}

// ---------------- K_fg: f,g GEMM -> frag-packed stores ----------------
__global__ __launch_bounds__(512) void k_fg(
    const short* __restrict__ xthi, const short* __restrict__ xtlo,
    const short* __restrict__ whi, const short* __restrict__ wlo,
    const float* __restrict__ bfv, const float* __restrict__ bgv,
    short* __restrict__ ffh, short* __restrict__ ffl,
    short* __restrict__ gfh, short* __restrict__ gfl) {
  int b = blockIdx.y, n0 = blockIdx.x * 64;
  int t = threadIdx.x, w = t >> 6, lane = t & 63, l15 = lane & 15, q = lane >> 4;
  int wr = w & 3, wh = w >> 2;  // row group / o-half (0=f,1=g)
  const short* ah = xthi + ((size_t)b * Nq + n0 + wr * 16 + l15) * Cq;
  const short* al = xtlo + ((size_t)b * Nq + n0 + wr * 16 + l15) * Cq;
  f32x4 z = {0.f, 0.f, 0.f, 0.f};
  f32x4 acc[4] = {z, z, z, z};
  for (int ks = 0; ks < 16; ks++) {
    bf16x8 Ahi = *(const bf16x8*)(ah + ks * 32 + q * 8);
    bf16x8 Alo = *(const bf16x8*)(al + ks * 32 + q * 8);
#pragma unroll
    for (int os = 0; os < 4; os++) {
      int o = wh * 64 + os * 16 + l15;
      bf16x8 Bhi = *(const bf16x8*)(whi + o * 512 + ks * 32 + q * 8);
      bf16x8 Blo = *(const bf16x8*)(wlo + o * 512 + ks * 32 + q * 8);
      acc[os] = MFMA16(Alo, Bhi, acc[os]);
      acc[os] = MFMA16(Ahi, Blo, acc[os]);
      acc[os] = MFMA16(Ahi, Bhi, acc[os]);
    }
  }
#pragma unroll
  for (int os = 0; os < 4; os++) {
#pragma unroll
    for (int r = 0; r < 4; r++) {
      int o = os * 16 + l15;                 // 0..63 within f or g
      int n = n0 + wr * 16 + q * 4 + r;
      float v = acc[os][r] + (wh == 0 ? bfv[o] : bgv[o]);
      size_t off = ((size_t)((b * 256 + (n >> 4)) * 2 + (o >> 5))) * 512
                 + (((o >> 3) & 3) * 16 + (n & 15)) * 8 + (o & 7);
      short h = f2bf(v);
      short lo = f2bf(v - bf2f(h));
      if (wh == 0) { ffh[off] = h; ffl[off] = lo; }
      else         { gfh[off] = h; gfl[off] = lo; }
    }
  }
}

// ---------------- K_stats: l_i partials + P^T = bf16(exp(S)) frag-packed ----
__global__ __launch_bounds__(512) void k_stats(
    const short* __restrict__ ffh, const short* __restrict__ ffl,
    const short* __restrict__ gfh, const short* __restrict__ gfl,
    float* __restrict__ lsum4, short* __restrict__ pmat) {
  int jch = blockIdx.x, jc = jch * 1024, i0 = blockIdx.y * 64, b = blockIdx.z;
  int t = threadIdx.x, w = t >> 6, lane = t & 63, l15 = lane & 15, q = lane >> 4;
  bf16x8 Ahi[4][2], Alo[4][2];
#pragma unroll
  for (int ig = 0; ig < 4; ig++)
#pragma unroll
    for (int ss = 0; ss < 2; ss++) {
      size_t base = fg_frag(b, (i0 >> 4) + ig, ss) + lane * 8;
      Ahi[ig][ss] = *(const bf16x8*)(ffh + base);
      Alo[ig][ss] = *(const bf16x8*)(ffl + base);
    }
  float ls[16];
#pragma unroll
  for (int a = 0; a < 16; a++) ls[a] = 0.f;
  f32x4 z = {0.f, 0.f, 0.f, 0.f};
  for (int jt = 0; jt < 8; jt++) {
    int tj = (jc >> 4) + w * 8 + jt;
    bf16x8 GBh[2], GBl[2];
#pragma unroll
    for (int ss = 0; ss < 2; ss++) {
      size_t base = fg_frag(b, tj, ss) + lane * 8;
      GBh[ss] = *(const bf16x8*)(gfh + base);
      GBl[ss] = *(const bf16x8*)(gfl + base);
    }
#pragma unroll
    for (int ig = 0; ig < 4; ig++) {
      f32x4 sh = z, sl = z;
#pragma unroll
      for (int ss = 0; ss < 2; ss++) {
        sl = MFMA16(Alo[ig][ss], GBh[ss], sl);
        sl = MFMA16(Ahi[ig][ss], GBl[ss], sl);
        sh = MFMA16(Ahi[ig][ss], GBh[ss], sh);
      }
      float ev[4];
#pragma unroll
      for (int r = 0; r < 4; r++) {
        ev[r] = __expf(sh[r] + sl[r]);
        ls[ig * 4 + r] += ev[r];
      }
      uint2 pv;
      pv.x = (unsigned)(unsigned short)f2bf(ev[0]) |
             ((unsigned)(unsigned short)f2bf(ev[1]) << 16);
      pv.y = (unsigned)(unsigned short)f2bf(ev[2]) |
             ((unsigned)(unsigned short)f2bf(ev[3]) << 16);
      size_t pb = p_frag(b, tj, (i0 >> 5) + (ig >> 1)) +
                  (size_t)(((ig & 1) * 2 + (q >> 1)) * 128 + l15 * 8 + (q & 1) * 4);
      *(uint2*)(pmat + pb) = pv;
    }
  }
#pragma unroll
  for (int m = 1; m < 16; m <<= 1) {
#pragma unroll
    for (int a = 0; a < 16; a++) ls[a] += __shfl_xor(ls[a], m, 64);
  }
  __shared__ float part[8][64];
  if (l15 == 0) {
#pragma unroll
    for (int ig = 0; ig < 4; ig++)
#pragma unroll
      for (int r = 0; r < 4; r++) part[w][ig * 16 + q * 4 + r] = ls[ig * 4 + r];
  }
  __syncthreads();
  if (t < 64) {
    float s = 0.f;
#pragma unroll
    for (int ww = 0; ww < 8; ww++) s += part[ww][t];
    lsum4[(size_t)jch * 16384 + (size_t)b * Nq + i0 + t] = s;
  }
}

// ---------------- K_hv: hvfrag = frag-packed bf16((Wh.x + bh)/l) ----------------
__global__ __launch_bounds__(512) void k_hv(
    const short* __restrict__ whb, const short* __restrict__ xthi,
    const float* __restrict__ bhv, const float* __restrict__ lsum4,
    short* __restrict__ hvf) {
  int si = blockIdx.x, b = blockIdx.y;
  int t = threadIdx.x, w = t >> 6, lane = t & 63, l15 = lane & 15, q = lane >> 4;
  int c0 = w * 64;
  const short* ar0 = xthi + ((size_t)b * Nq + si * 32 + l15) * Cq;
  const short* ar1 = ar0 + 16 * Cq;
  f32x4 z = {0.f, 0.f, 0.f, 0.f};
  f32x4 acc[2][4];
#pragma unroll
  for (int a = 0; a < 2; a++)
#pragma unroll
    for (int c = 0; c < 4; c++) acc[a][c] = z;
  for (int ks = 0; ks < 16; ks++) {
    bf16x8 A0 = *(const bf16x8*)(ar0 + ks * 32 + q * 8);
    bf16x8 A1 = *(const bf16x8*)(ar1 + ks * 32 + q * 8);
#pragma unroll
    for (int ct = 0; ct < 4; ct++) {
      bf16x8 Bv = *(const bf16x8*)(whb + (size_t)(c0 + ct * 16 + l15) * 512 + ks * 32 + q * 8);
      acc[0][ct] = MFMA16(A0, Bv, acc[0][ct]);
      acc[1][ct] = MFMA16(A1, Bv, acc[1][ct]);
    }
  }
  float li[2][4];
#pragma unroll
  for (int it = 0; it < 2; it++)
#pragma unroll
    for (int r = 0; r < 4; r++) {
      size_t idx = (size_t)b * Nq + si * 32 + it * 16 + q * 4 + r;
      float s = lsum4[idx] + lsum4[16384 + idx] + lsum4[32768 + idx] + lsum4[49152 + idx];
      li[it][r] = 1.0f / s;
    }
  int src0 = ((q & 1) << 5) + l15;
  int src1 = src0 + 16;
  int hiSel = q >> 1;
#pragma unroll
  for (int ct = 0; ct < 4; ct++) {
    float bias = bhv[c0 + ct * 16 + l15];
    unsigned u01[2], u23[2];
#pragma unroll
    for (int it = 0; it < 2; it++) {
      float v0 = (acc[it][ct][0] + bias) * li[it][0];
      float v1 = (acc[it][ct][1] + bias) * li[it][1];
      float v2 = (acc[it][ct][2] + bias) * li[it][2];
      float v3 = (acc[it][ct][3] + bias) * li[it][3];
      u01[it] = (unsigned)(unsigned short)f2bf(v0) | ((unsigned)(unsigned short)f2bf(v1) << 16);
      u23[it] = (unsigned)(unsigned short)f2bf(v2) | ((unsigned)(unsigned short)f2bf(v3) << 16);
    }
    unsigned a0 = __shfl((int)u01[0], src0), b0 = __shfl((int)u01[1], src0);
    unsigned a1 = __shfl((int)u23[0], src0), b1 = __shfl((int)u23[1], src0);
    unsigned a2 = __shfl((int)u01[0], src1), b2 = __shfl((int)u01[1], src1);
    unsigned a3 = __shfl((int)u23[0], src1), b3 = __shfl((int)u23[1], src1);
    uint4 st;
    st.x = hiSel ? b0 : a0;
    st.y = hiSel ? b1 : a1;
    st.z = hiSel ? b2 : a2;
    st.w = hiSel ? b3 : a3;
    *(uint4*)(hvf + hv_frag(b, (c0 >> 4) + ct, si) + (size_t)lane * 8) = st;
  }
}

// ---------------- K_pv: out = gamma * hv2 @ P + x (LDS-staged GEMM) ----------
// Grid 256 = (b 4) x (ch 2) x (jq 32: j-tile 128); combo = L&7 -> XCD.
// 512 thr, 8 waves: cg = w&3 (64-c strip of the 256-c half), jg = w>>2
// (64-j half of the 128-j tile). acc[4][4]. LDS: 2 bufs x 24 tiles x 1KB
// = 48KB (HV slots 0..15 = c-tiles; P slots 16..23 = j-tiles), one si/step.
// Per step k: STAGE(k+1) [3 gload_lds(16B)/wave]; vmcnt(3) (drains step k;
// k=127 -> vmcnt(0)); s_barrier; COMPUTE (8 ds_read_b128 + 16 MFMA/wave);
// lgkmcnt(0); s_barrier. Loads ride 1 step ahead, never drained to 0
// mid-loop (T4). si ascending -> bitwise == R13-verified k_pv.
__global__ __launch_bounds__(512, 2) void k_pv(
    const short* __restrict__ hvf, const short* __restrict__ pmat,
    const float* __restrict__ x, const float* __restrict__ gp,
    float* __restrict__ out) {
  int L = blockIdx.x;
  int combo = L & 7;                      // -> XCD id under round-robin dispatch
  int b = combo >> 1, ch = combo & 1;     // batch, c-half
  int jq = L >> 3;                        // 0..31
  int j0 = jq * 128;
  int t = threadIdx.x, w = t >> 6, lane = t & 63, l15 = lane & 15, q = lane >> 4;
  int cg = w & 3, jg = w >> 2;            // c-strip, j-half
  __shared__ __align__(16) short lds[2][24][512];   // 48 KB
  float gamma = gp[0];
  f32x4 z = {0.f, 0.f, 0.f, 0.f};
  f32x4 acc[4][4];                        // [ct][jt]
#pragma unroll
  for (int a = 0; a < 4; a++)
#pragma unroll
    for (int bb = 0; bb < 4; bb++) acc[a][bb] = z;

  int jp0 = j0 >> 4;                      // first P j-tile of this block
  auto STAGE = [&](int si, int bufIdx) {
#pragma unroll
    for (int i = 0; i < 3; i++) {
      int s = w * 3 + i;                  // 0..23
      const short* src = (s < 16)
          ? (hvf + hv_frag(b, ch * 16 + s, si))
          : (pmat + p_frag(b, jp0 + (s - 16), si));
      gl_lds16(src + (size_t)lane * 8, &lds[bufIdx][s][0]);
    }
  };
  auto COMPUTE = [&](int bufIdx) {
    bf16x8 HV[4], PB[4];
#pragma unroll
    for (int ct = 0; ct < 4; ct++)
      HV[ct] = *(const bf16x8*)&lds[bufIdx][cg * 4 + ct][lane * 8];
#pragma unroll
    for (int jt = 0; jt < 4; jt++)
      PB[jt] = *(const bf16x8*)&lds[bufIdx][16 + jg * 4 + jt][lane * 8];
#pragma unroll
    for (int ct = 0; ct < 4; ct++)
#pragma unroll
      for (int jt = 0; jt < 4; jt++)
        acc[ct][jt] = MFMA16(HV[ct], PB[jt], acc[ct][jt]);
  };

  STAGE(0, 0);
  for (int k = 0; k < 128; k++) {
    int bi = k & 1;
    if (k < 127) {
      STAGE(k + 1, 1 - bi);
      asm volatile("s_waitcnt vmcnt(3)" ::: "memory");
    } else {
      asm volatile("s_waitcnt vmcnt(0)" ::: "memory");
    }
    __builtin_amdgcn_s_barrier();
    COMPUTE(bi);
    asm volatile("s_waitcnt lgkmcnt(0)" ::: "memory");
    __builtin_amdgcn_s_barrier();
  }

#pragma unroll
  for (int ct = 0; ct < 4; ct++) {
#pragma unroll
    for (int jt = 0; jt < 4; jt++) {
#pragma unroll
      for (int r = 0; r < 4; r++) {
        int c = ch * 256 + cg * 64 + ct * 16 + q * 4 + r;
        int j = j0 + jg * 64 + jt * 16 + l15;
        size_t off = ((size_t)b * Cq + c) * Nq + j;
        out[off] = gamma * acc[ct][jt][r] + x[off];
      }
    }
  }
}

extern "C" void kernel_launch(void* const* d_in, const int* in_sizes, int n_in,
                              void* d_out, int out_size, void* d_ws, size_t ws_size,
                              hipStream_t stream) {
  (void)in_sizes; (void)n_in; (void)out_size; (void)ws_size;
  const float* x  = (const float*)d_in[0];
  const float* Wf = (const float*)d_in[1];
  const float* bf = (const float*)d_in[2];
  const float* Wg = (const float*)d_in[3];
  const float* bg = (const float*)d_in[4];
  const float* Wh = (const float*)d_in[5];
  const float* bh = (const float*)d_in[6];
  const float* gm = (const float*)d_in[7];
  float* out = (float*)d_out;
  char* ws = (char*)d_ws;
  // Workspace layout (bytes); total 193,986,560 (~185 MB)
  short* xthi  = (short*)(ws);               // 16,777,216  (B,N,C) bf16 hi
  short* xtlo  = (short*)(ws + 16777216);    // 16,777,216  lo
  short* ffh   = (short*)(ws + 33554432);    //  2,097,152  f frag-packed hi
  short* ffl   = (short*)(ws + 35651584);    //  2,097,152  f lo
  short* gfh   = (short*)(ws + 37748736);    //  2,097,152  g frag-packed hi
  short* gfl   = (short*)(ws + 39845888);    //  2,097,152  g lo
  short* whi   = (short*)(ws + 41943040);    //    131,072  (128,512)
  short* wlo   = (short*)(ws + 42074112);    //    131,072
  short* whb   = (short*)(ws + 42205184);    //    524,288  (512,512)
  float* lsum4 = (float*)(ws + 42729472);    //    262,144  (4 chunks, B, N)
  short* hvf   = (short*)(ws + 42991616);    // 16,777,216  hv frag-packed bf16
  short* pmat  = (short*)(ws + 59768832);    // 134,217,728 P^T frag-packed bf16

  hipLaunchKernelGGL(k_prepw, dim3(1024), dim3(256), 0, stream, Wf, Wg, Wh, whi, wlo, whb);
  hipLaunchKernelGGL(k_xpose, dim3(64, 8, 4), dim3(256), 0, stream, x, xthi, xtlo);
  hipLaunchKernelGGL(k_fg, dim3(64, 4), dim3(512), 0, stream,
                     xthi, xtlo, whi, wlo, bf, bg, ffh, ffl, gfh, gfl);
  hipLaunchKernelGGL(k_stats, dim3(4, 64, 4), dim3(512), 0, stream,
                     ffh, ffl, gfh, gfl, lsum4, pmat);
  hipLaunchKernelGGL(k_hv, dim3(128, 4), dim3(512), 0, stream, whb, xthi, bh, lsum4, hvf);
  hipLaunchKernelGGL(k_pv, dim3(256), dim3(512), 0, stream, hvf, pmat, x, gm, out);
}